// Round 15
// baseline (78.961 us; speedup 1.0000x reference)
//
#include <hip/hip_runtime.h>

#define N_NODES 10000
#define N_EDGES 320000
#define N_PAIRS 8192
#define IN_CH   128
#define HIDDEN  256
#define K_DIM   256   // 2*IN_CH
#define WPR     320   // u32 words per adjacency bitset row (320*32 = 10240 >= 10000)
#define WPR4    (WPR / 4)
#define TILE_B  16    // pairs per block; grid 512, 512 threads/block
#define CN_CAP  128   // covers i==j pairs (cnt ~ Poisson(64)); overflow ~P<1e-15
#define ZERO_BLOCKS (N_NODES * WPR / 4 / 256)   // 3125 (uint4 units)
#define PACK_BLOCKS 32
#define ADJ_BLOCKS  (N_EDGES / 256)             // 1250

typedef __attribute__((ext_vector_type(8))) short  short8;   // 8 bf16 (4 VGPRs)
typedef __attribute__((ext_vector_type(4))) float  f32x4;    // MFMA accumulator

static __device__ inline short f2bf(float f) {
    union { float f; unsigned u; } c; c.f = f;
    unsigned r = (c.u + 0x7FFFu + ((c.u >> 16) & 1u)) >> 16;   // RNE
    return (short)r;
}

// ---------------------------------------------- zero adjacency + pack W1
// B-fragment for (k-step ks, n-tile t): lane l, elem e holds
//   W1[n = t*16 + (l&15)][k = ks*32 + (l>>4)*8 + e]   (bf16)
// at W1B[((ks*16 + t)*64 + l)*8 + e].
__global__ __launch_bounds__(256) void zero_pack_kernel(uint4* __restrict__ adj4,
                                                        const float* __restrict__ W1,
                                                        short* __restrict__ W1B) {
    int bid = blockIdx.x;
    int tid = threadIdx.x;
    if (bid < ZERO_BLOCKS) {
        adj4[(size_t)bid * 256 + tid] = make_uint4(0u, 0u, 0u, 0u);
    } else {
        int t2 = (bid - ZERO_BLOCKS) * 256 + tid;   // 0..8191
        int ks = t2 >> 10;                          // 0..7
        int t  = (t2 >> 6) & 15;                    // n-tile 0..15
        int l  = t2 & 63;                           // lane
        int n  = t * 16 + (l & 15);
        int kb = ks * 32 + ((l >> 4) << 3);
        const float* src = W1 + (size_t)n * K_DIM + kb;
        short* dst = W1B + ((size_t)(ks * 16 + t) * 64 + l) * 8;
#pragma unroll
        for (int e = 0; e < 8; ++e) dst[e] = f2bf(src[e]);
    }
}

// ---------------------------------------------------------------- adjacency
__global__ __launch_bounds__(256) void build_adj_kernel(const int* __restrict__ ei,
                                                        unsigned int* __restrict__ adj) {
    int e = blockIdx.x * blockDim.x + threadIdx.x;   // grid*block == N_EDGES exactly
    int u = ei[e];
    int v = ei[N_EDGES + e];
    atomicOr(&adj[(size_t)u * WPR + (v >> 5)], 1u << (v & 31));
    atomicOr(&adj[(size_t)v * WPR + (u >> 5)], 1u << (u & 31));
}

// ------------------------------------------------- fused pair-xs + MFMA MLP
__global__ __launch_bounds__(512) void fused_kernel(const float* __restrict__ x,
                                                    const int* __restrict__ tei,
                                                    const unsigned int* __restrict__ adj,
                                                    const short* __restrict__ W1B,
                                                    const float* __restrict__ b1,
                                                    const float* __restrict__ W2,
                                                    const float* __restrict__ b2,
                                                    float* __restrict__ out) {
    // xs as float4 units: unit u of row b at b*64 + (u ^ (b&7))
    __shared__ float4 s_xs4[TILE_B * 64];     // 16 KB
    __shared__ int    s_ij[TILE_B][2];
    __shared__ int    s_cnt[TILE_B];
    __shared__ int    s_cnl[TILE_B][CN_CAP];  // 8 KB
    __shared__ float  s_part[TILE_B][8];

    const int tid = threadIdx.x;
    const int p0 = blockIdx.x * TILE_B;

    if (tid < TILE_B) {
        s_ij[tid][0] = tei[p0 + tid];
        s_ij[tid][1] = tei[N_PAIRS + p0 + tid];
        s_cnt[tid] = 0;
    }
    // zero CN half (units 32..63 of each row; XOR-swizzle is a bijection on it)
    {
        int zb = tid >> 5, zu = 32 + (tid & 31);
        s_xs4[zb * 64 + zu] = make_float4(0.f, 0.f, 0.f, 0.f);
    }
    __syncthreads();

    // ---- phase 1: intersection + xij (32 threads per pair; pair within one wave)
    const int b = tid >> 5;
    const int s = tid & 31;
    const int i = s_ij[b][0];
    const int j = s_ij[b][1];

    const float4* xi4 = (const float4*)(x + (size_t)i * IN_CH);
    const float4* xj4 = (const float4*)(x + (size_t)j * IN_CH);
    float4 va = xi4[s];                      // issue early
    float4 vb = xj4[s];

    const uint4* ri4 = (const uint4*)(adj + (size_t)i * WPR);
    const uint4* rj4 = (const uint4*)(adj + (size_t)j * WPR);
    for (int q = s; q < WPR4; q += 32) {     // 2-3 iterations
        uint4 a = ri4[q];
        uint4 c = rj4[q];
        unsigned int m[4] = { a.x & c.x, a.y & c.y, a.z & c.z, a.w & c.w };
#pragma unroll
        for (int ww = 0; ww < 4; ++ww) {
            unsigned int mm = m[ww];
            while (mm) {
                int bit = __builtin_ctz(mm);
                mm &= mm - 1;
                int n = q * 128 + ww * 32 + bit;
                int pos = atomicAdd(&s_cnt[b], 1);
                if (pos < CN_CAP) {
                    s_cnl[b][pos] = n;
                } else {
                    // overflow (deg>128 self-pair; ~never): swizzle-aware LDS atomics
                    const float* xn = x + (size_t)n * IN_CH;
                    for (int d = 0; d < IN_CH; ++d) {
                        int u = 32 + (d >> 2);
                        float* base = (float*)&s_xs4[b * 64 + (u ^ (b & 7))];
                        atomicAdd(&base[d & 3], xn[d]);
                    }
                }
            }
        }
    }

    // xij: unit s of row b
    s_xs4[b * 64 + (s ^ (b & 7))] =
        make_float4(va.x * vb.x, va.y * vb.y, va.z * vb.z, va.w * vb.w);

    // cn_emb: slot (zero + overflow) + list, 4 independent load chains
    {
        int cnt = s_cnt[b];                  // same-wave LDS ops: ordered
        if (cnt > CN_CAP) cnt = CN_CAP;
        int u = (32 + s) ^ (b & 7);
        float4 d0 = s_xs4[b * 64 + u];
        float4 d1 = make_float4(0.f, 0.f, 0.f, 0.f);
        float4 d2 = make_float4(0.f, 0.f, 0.f, 0.f);
        float4 d3 = make_float4(0.f, 0.f, 0.f, 0.f);
        int c = 0;
        for (; c + 4 <= cnt; c += 4) {
            const float4* q0 = (const float4*)(x + (size_t)s_cnl[b][c]     * IN_CH);
            const float4* q1 = (const float4*)(x + (size_t)s_cnl[b][c + 1] * IN_CH);
            const float4* q2 = (const float4*)(x + (size_t)s_cnl[b][c + 2] * IN_CH);
            const float4* q3 = (const float4*)(x + (size_t)s_cnl[b][c + 3] * IN_CH);
            float4 v0 = q0[s], v1 = q1[s], v2 = q2[s], v3 = q3[s];
            d0 = make_float4(d0.x + v0.x, d0.y + v0.y, d0.z + v0.z, d0.w + v0.w);
            d1 = make_float4(d1.x + v1.x, d1.y + v1.y, d1.z + v1.z, d1.w + v1.w);
            d2 = make_float4(d2.x + v2.x, d2.y + v2.y, d2.z + v2.z, d2.w + v2.w);
            d3 = make_float4(d3.x + v3.x, d3.y + v3.y, d3.z + v3.z, d3.w + v3.w);
        }
        for (; c < cnt; ++c) {
            const float4* q0 = (const float4*)(x + (size_t)s_cnl[b][c] * IN_CH);
            float4 v0 = q0[s];
            d0 = make_float4(d0.x + v0.x, d0.y + v0.y, d0.z + v0.z, d0.w + v0.w);
        }
        d0 = make_float4(d0.x + d1.x + d2.x + d3.x,
                         d0.y + d1.y + d2.y + d3.y,
                         d0.z + d1.z + d2.z + d3.z,
                         d0.w + d1.w + d2.w + d3.w);
        s_xs4[b * 64 + u] = d0;
    }
    __syncthreads();

    // ---- phase 2: MFMA. wave w covers n-tiles {2w, 2w+1}, all 16 pairs.
    const int w    = tid >> 6;       // wave 0..7
    const int lane = tid & 63;
    const int t0 = w * 2;
    const int mr = lane & 15;   // A row = pair
    const int kb = lane >> 4;   // k-block 0..3

    f32x4 acc0 = {0.f, 0.f, 0.f, 0.f};
    f32x4 acc1 = {0.f, 0.f, 0.f, 0.f};

    const short8* W1B8 = (const short8*)W1B;
#pragma unroll
    for (int ks = 0; ks < 8; ++ks) {
        // A-frag: lane holds k = ks*32 + kb*8 + e of row mr (float4 units f0, f0+1)
        int f0 = ks * 8 + kb * 2;
        float4 x0 = s_xs4[mr * 64 + (f0 ^ (mr & 7))];
        float4 x1 = s_xs4[mr * 64 + ((f0 + 1) ^ (mr & 7))];
        short8 af;
        af[0] = f2bf(x0.x); af[1] = f2bf(x0.y); af[2] = f2bf(x0.z); af[3] = f2bf(x0.w);
        af[4] = f2bf(x1.x); af[5] = f2bf(x1.y); af[6] = f2bf(x1.z); af[7] = f2bf(x1.w);
        int fb = (ks * 16 + t0) * 64 + lane;
        short8 bf0 = W1B8[fb];
        short8 bf1 = W1B8[fb + 64];
        acc0 = __builtin_amdgcn_mfma_f32_16x16x32_bf16(af, bf0, acc0, 0, 0, 0);
        acc1 = __builtin_amdgcn_mfma_f32_16x16x32_bf16(af, bf1, acc1, 0, 0, 0);
    }

    // ---- epilogue: relu + layer 2 (fp32), reduce over h
    // C layout: col = lane&15 (n within tile), row = (lane>>4)*4 + reg (pair)
    const int ncol = lane & 15;
    const float b10 = b1[t0 * 16 + ncol];
    const float b11 = b1[(t0 + 1) * 16 + ncol];
    const float w20 = W2[t0 * 16 + ncol];
    const float w21 = W2[(t0 + 1) * 16 + ncol];

    float sum[4];
#pragma unroll
    for (int r = 0; r < 4; ++r)
        sum[r] = w20 * fmaxf(acc0[r] + b10, 0.f) + w21 * fmaxf(acc1[r] + b11, 0.f);

#pragma unroll
    for (int r = 0; r < 4; ++r) {
        float v = sum[r];
        v += __shfl_xor(v, 1);
        v += __shfl_xor(v, 2);
        v += __shfl_xor(v, 4);
        v += __shfl_xor(v, 8);
        if ((lane & 15) == 0) s_part[kb * 4 + r][w] = v;
    }
    __syncthreads();

    if (tid < TILE_B) {
        float r = b2[0];
#pragma unroll
        for (int ww = 0; ww < 8; ++ww) r += s_part[tid][ww];
        out[p0 + tid] = r;
    }
}

// -------------------------------------------------------------------- launch
extern "C" void kernel_launch(void* const* d_in, const int* in_sizes, int n_in,
                              void* d_out, int out_size, void* d_ws, size_t ws_size,
                              hipStream_t stream) {
    const float* x   = (const float*)d_in[0];
    const int*   ei  = (const int*)d_in[1];
    const int*   tei = (const int*)d_in[2];
    const float* W1  = (const float*)d_in[3];
    const float* b1  = (const float*)d_in[4];
    const float* W2  = (const float*)d_in[5];
    const float* b2  = (const float*)d_in[6];
    float* out = (float*)d_out;

    unsigned char* ws = (unsigned char*)d_ws;
    const size_t adj_bytes = (size_t)N_NODES * WPR * sizeof(unsigned int);   // 12.8 MB
    unsigned int* adj = (unsigned int*)ws;
    short* W1B = (short*)(ws + adj_bytes);                                   // 128 KB bf16

    zero_pack_kernel<<<ZERO_BLOCKS + PACK_BLOCKS, 256, 0, stream>>>((uint4*)adj, W1, W1B);
    // MEASUREMENT PROBE (this round only): build_adj is idempotent (atomicOr
    // sets identical bits), so a second launch is correctness-neutral and the
    // total-duration delta vs round 12 (54.1 us) == T_build + launch overhead.
    build_adj_kernel<<<ADJ_BLOCKS, 256, 0, stream>>>(ei, adj);
    build_adj_kernel<<<ADJ_BLOCKS, 256, 0, stream>>>(ei, adj);
    fused_kernel<<<N_PAIRS / TILE_B, 512, 0, stream>>>(x, tei, adj, W1B, b1, W2, b2, out);
}

// Round 16
// 56.313 us; speedup vs baseline: 1.4022x; 1.4022x over previous
//
#include <hip/hip_runtime.h>

#define N_NODES 10000
#define N_EDGES 320000
#define N_PAIRS 8192
#define IN_CH   128
#define HIDDEN  256
#define K_DIM   256   // 2*IN_CH
#define WPR     320   // u32 words per adjacency bitset row (320*32 = 10240 >= 10000)
#define WPR4    (WPR / 4)
#define TILE_B  16    // pairs per block; 512 threads/block
#define CN_CAP  128   // covers i==j pairs (cnt ~ Poisson(64)); overflow ~P<1e-15
#define ZERO_BLOCKS (N_NODES * WPR / 4 / 256)   // 3125 (uint4 units)
#define PACK_BLOCKS 32
#define XIJ_BLOCKS  (N_PAIRS / TILE_B)          // 512 (xij partial GEMM)
#define BUILD_BLOCKS (N_EDGES / 512)            // 625 (edge scatter, 512 thr)

typedef __attribute__((ext_vector_type(8))) short  short8;   // 8 bf16 (4 VGPRs)
typedef __attribute__((ext_vector_type(4))) float  f32x4;    // MFMA accumulator

static __device__ inline short f2bf(float f) {
    union { float f; unsigned u; } c; c.f = f;
    unsigned r = (c.u + 0x7FFFu + ((c.u >> 16) & 1u)) >> 16;   // RNE
    return (short)r;
}

// ---------------------------------------------- zero adjacency + pack W1
// B-fragment for (k-step ks, n-tile t): lane l, elem e holds
//   W1[n = t*16 + (l&15)][k = ks*32 + (l>>4)*8 + e]   (bf16)
// at W1B[((ks*16 + t)*64 + l)*8 + e].
__global__ __launch_bounds__(256) void zero_pack_kernel(uint4* __restrict__ adj4,
                                                        const float* __restrict__ W1,
                                                        short* __restrict__ W1B) {
    int bid = blockIdx.x;
    int tid = threadIdx.x;
    if (bid < ZERO_BLOCKS) {
        adj4[(size_t)bid * 256 + tid] = make_uint4(0u, 0u, 0u, 0u);
    } else {
        int t2 = (bid - ZERO_BLOCKS) * 256 + tid;   // 0..8191
        int ks = t2 >> 10;                          // 0..7
        int t  = (t2 >> 6) & 15;                    // n-tile 0..15
        int l  = t2 & 63;                           // lane
        int n  = t * 16 + (l & 15);
        int kb = ks * 32 + ((l >> 4) << 3);
        const float* src = W1 + (size_t)n * K_DIM + kb;
        short* dst = W1B + ((size_t)(ks * 16 + t) * 64 + l) * 8;
#pragma unroll
        for (int e = 0; e < 8; ++e) dst[e] = f2bf(src[e]);
    }
}

// ---------------- heterogeneous: xij partial GEMM  ||  edge scatter ----------
// blocks [0, XIJ_BLOCKS): K1[pair-tile] += W1a . xij   (no adj dependency)
// blocks [XIJ_BLOCKS, XIJ_BLOCKS+BUILD_BLOCKS): atomicOr edge scatter.
// Independent block families overlap: GEMM hides under the atomic-bound build.
__global__ __launch_bounds__(512) void mixed_kernel(const float* __restrict__ x,
                                                    const int* __restrict__ tei,
                                                    const int* __restrict__ ei,
                                                    unsigned int* __restrict__ adj,
                                                    const short* __restrict__ W1B,
                                                    f32x4* __restrict__ K1) {
    const int tid = threadIdx.x;
    if (blockIdx.x >= XIJ_BLOCKS) {
        int e = (blockIdx.x - XIJ_BLOCKS) * 512 + tid;   // exact: 625*512 == N_EDGES
        int u = ei[e];
        int v = ei[N_EDGES + e];
        atomicOr(&adj[(size_t)u * WPR + (v >> 5)], 1u << (v & 31));
        atomicOr(&adj[(size_t)v * WPR + (u >> 5)], 1u << (u & 31));
        return;
    }

    // xij half: units 0..31 of row b at b*32 + (u ^ (b&7))
    __shared__ float4 s_xij[TILE_B * 32];    // 8 KB
    const int p0 = blockIdx.x * TILE_B;

    const int b = tid >> 5;      // pair 0..15
    const int s = tid & 31;      // unit
    const int i = tei[p0 + b];
    const int j = tei[N_PAIRS + p0 + b];
    float4 va = ((const float4*)(x + (size_t)i * IN_CH))[s];
    float4 vb = ((const float4*)(x + (size_t)j * IN_CH))[s];
    s_xij[b * 32 + (s ^ (b & 7))] =
        make_float4(va.x * vb.x, va.y * vb.y, va.z * vb.z, va.w * vb.w);
    __syncthreads();

    // wave w covers n-tiles {2w, 2w+1}; ks = 0..3 (k = 0..127 = xij features)
    const int w    = tid >> 6;
    const int lane = tid & 63;
    const int t0 = w * 2;
    const int mr = lane & 15;
    const int kb = lane >> 4;

    f32x4 acc0 = {0.f, 0.f, 0.f, 0.f};
    f32x4 acc1 = {0.f, 0.f, 0.f, 0.f};
    const short8* W1B8 = (const short8*)W1B;
#pragma unroll
    for (int ks = 0; ks < 4; ++ks) {
        int f0 = ks * 8 + kb * 2;                     // unit 0..30
        float4 x0 = s_xij[mr * 32 + (f0 ^ (mr & 7))];
        float4 x1 = s_xij[mr * 32 + ((f0 + 1) ^ (mr & 7))];
        short8 af;
        af[0] = f2bf(x0.x); af[1] = f2bf(x0.y); af[2] = f2bf(x0.z); af[3] = f2bf(x0.w);
        af[4] = f2bf(x1.x); af[5] = f2bf(x1.y); af[6] = f2bf(x1.z); af[7] = f2bf(x1.w);
        int fb = (ks * 16 + t0) * 64 + lane;
        short8 bf0 = W1B8[fb];
        short8 bf1 = W1B8[fb + 64];
        acc0 = __builtin_amdgcn_mfma_f32_16x16x32_bf16(af, bf0, acc0, 0, 0, 0);
        acc1 = __builtin_amdgcn_mfma_f32_16x16x32_bf16(af, bf1, acc1, 0, 0, 0);
    }
    // K1 in C-fragment layout: [block][wave][acc#][lane]
    K1[((blockIdx.x * 8 + w) * 2 + 0) * 64 + lane] = acc0;
    K1[((blockIdx.x * 8 + w) * 2 + 1) * 64 + lane] = acc1;
}

// ------------------------------------------------- fused2: CN + K=128 MFMA
__global__ __launch_bounds__(512) void fused2_kernel(const float* __restrict__ x,
                                                     const int* __restrict__ tei,
                                                     const unsigned int* __restrict__ adj,
                                                     const short* __restrict__ W1B,
                                                     const f32x4* __restrict__ K1,
                                                     const float* __restrict__ b1,
                                                     const float* __restrict__ W2,
                                                     const float* __restrict__ b2,
                                                     float* __restrict__ out) {
    // cn half only: unit u (0..31) of row b at b*32 + (u ^ (b&7))
    __shared__ float4 s_cn[TILE_B * 32];      // 8 KB
    __shared__ int    s_ij[TILE_B][2];
    __shared__ int    s_cnt[TILE_B];
    __shared__ int    s_cnl[TILE_B][CN_CAP];  // 8 KB
    __shared__ float  s_part[TILE_B][8];

    const int tid = threadIdx.x;
    const int p0 = blockIdx.x * TILE_B;

    if (tid < TILE_B) {
        s_ij[tid][0] = tei[p0 + tid];
        s_ij[tid][1] = tei[N_PAIRS + p0 + tid];
        s_cnt[tid] = 0;
    }
    // zero cn buffer (swizzle is bijective per row: zero linearly)
    {
        int zb = tid >> 5, zu = tid & 31;
        s_cn[zb * 32 + zu] = make_float4(0.f, 0.f, 0.f, 0.f);
    }
    __syncthreads();

    // ---- phase 1: intersection + CN gather (32 threads per pair)
    const int b = tid >> 5;
    const int s = tid & 31;
    const int i = s_ij[b][0];
    const int j = s_ij[b][1];

    const uint4* ri4 = (const uint4*)(adj + (size_t)i * WPR);
    const uint4* rj4 = (const uint4*)(adj + (size_t)j * WPR);
    for (int q = s; q < WPR4; q += 32) {     // 2-3 iterations
        uint4 a = ri4[q];
        uint4 c = rj4[q];
        unsigned int m[4] = { a.x & c.x, a.y & c.y, a.z & c.z, a.w & c.w };
#pragma unroll
        for (int ww = 0; ww < 4; ++ww) {
            unsigned int mm = m[ww];
            while (mm) {
                int bit = __builtin_ctz(mm);
                mm &= mm - 1;
                int n = q * 128 + ww * 32 + bit;
                int pos = atomicAdd(&s_cnt[b], 1);
                if (pos < CN_CAP) {
                    s_cnl[b][pos] = n;
                } else {
                    // overflow (deg>128 self-pair; ~never): swizzle-aware LDS atomics
                    const float* xn = x + (size_t)n * IN_CH;
                    for (int d = 0; d < IN_CH; ++d) {
                        int u = d >> 2;
                        float* base = (float*)&s_cn[b * 32 + (u ^ (b & 7))];
                        atomicAdd(&base[d & 3], xn[d]);
                    }
                }
            }
        }
    }

    // cn_emb: slot (zero + overflow) + list, 4 independent load chains
    {
        int cnt = s_cnt[b];                  // same-wave LDS ops: ordered
        if (cnt > CN_CAP) cnt = CN_CAP;
        int u = s ^ (b & 7);
        float4 d0 = s_cn[b * 32 + u];
        float4 d1 = make_float4(0.f, 0.f, 0.f, 0.f);
        float4 d2 = make_float4(0.f, 0.f, 0.f, 0.f);
        float4 d3 = make_float4(0.f, 0.f, 0.f, 0.f);
        int c = 0;
        for (; c + 4 <= cnt; c += 4) {
            const float4* q0 = (const float4*)(x + (size_t)s_cnl[b][c]     * IN_CH);
            const float4* q1 = (const float4*)(x + (size_t)s_cnl[b][c + 1] * IN_CH);
            const float4* q2 = (const float4*)(x + (size_t)s_cnl[b][c + 2] * IN_CH);
            const float4* q3 = (const float4*)(x + (size_t)s_cnl[b][c + 3] * IN_CH);
            float4 v0 = q0[s], v1 = q1[s], v2 = q2[s], v3 = q3[s];
            d0 = make_float4(d0.x + v0.x, d0.y + v0.y, d0.z + v0.z, d0.w + v0.w);
            d1 = make_float4(d1.x + v1.x, d1.y + v1.y, d1.z + v1.z, d1.w + v1.w);
            d2 = make_float4(d2.x + v2.x, d2.y + v2.y, d2.z + v2.z, d2.w + v2.w);
            d3 = make_float4(d3.x + v3.x, d3.y + v3.y, d3.z + v3.z, d3.w + v3.w);
        }
        for (; c < cnt; ++c) {
            const float4* q0 = (const float4*)(x + (size_t)s_cnl[b][c] * IN_CH);
            float4 v0 = q0[s];
            d0 = make_float4(d0.x + v0.x, d0.y + v0.y, d0.z + v0.z, d0.w + v0.w);
        }
        d0 = make_float4(d0.x + d1.x + d2.x + d3.x,
                         d0.y + d1.y + d2.y + d3.y,
                         d0.z + d1.z + d2.z + d3.z,
                         d0.w + d1.w + d2.w + d3.w);
        s_cn[b * 32 + u] = d0;
    }
    __syncthreads();

    // ---- phase 2: MFMA ks=4..7 (cn features), acc initialized from K1
    const int w    = tid >> 6;       // wave 0..7
    const int lane = tid & 63;
    const int t0 = w * 2;
    const int mr = lane & 15;   // A row = pair
    const int kb = lane >> 4;   // k-block 0..3

    f32x4 acc0 = K1[((blockIdx.x * 8 + w) * 2 + 0) * 64 + lane];
    f32x4 acc1 = K1[((blockIdx.x * 8 + w) * 2 + 1) * 64 + lane];

    const short8* W1B8 = (const short8*)W1B;
#pragma unroll
    for (int ks = 4; ks < 8; ++ks) {
        int f0 = ks * 8 + kb * 2 - 32;                 // cn unit 0..30
        float4 x0 = s_cn[mr * 32 + (f0 ^ (mr & 7))];
        float4 x1 = s_cn[mr * 32 + ((f0 + 1) ^ (mr & 7))];
        short8 af;
        af[0] = f2bf(x0.x); af[1] = f2bf(x0.y); af[2] = f2bf(x0.z); af[3] = f2bf(x0.w);
        af[4] = f2bf(x1.x); af[5] = f2bf(x1.y); af[6] = f2bf(x1.z); af[7] = f2bf(x1.w);
        int fb = (ks * 16 + t0) * 64 + lane;
        short8 bf0 = W1B8[fb];
        short8 bf1 = W1B8[fb + 64];
        acc0 = __builtin_amdgcn_mfma_f32_16x16x32_bf16(af, bf0, acc0, 0, 0, 0);
        acc1 = __builtin_amdgcn_mfma_f32_16x16x32_bf16(af, bf1, acc1, 0, 0, 0);
    }

    // ---- epilogue: relu + layer 2 (fp32), reduce over h
    // C layout: col = lane&15 (n within tile), row = (lane>>4)*4 + reg (pair)
    const int ncol = lane & 15;
    const float b10 = b1[t0 * 16 + ncol];
    const float b11 = b1[(t0 + 1) * 16 + ncol];
    const float w20 = W2[t0 * 16 + ncol];
    const float w21 = W2[(t0 + 1) * 16 + ncol];

    float sum[4];
#pragma unroll
    for (int r = 0; r < 4; ++r)
        sum[r] = w20 * fmaxf(acc0[r] + b10, 0.f) + w21 * fmaxf(acc1[r] + b11, 0.f);

#pragma unroll
    for (int r = 0; r < 4; ++r) {
        float v = sum[r];
        v += __shfl_xor(v, 1);
        v += __shfl_xor(v, 2);
        v += __shfl_xor(v, 4);
        v += __shfl_xor(v, 8);
        if ((lane & 15) == 0) s_part[kb * 4 + r][w] = v;
    }
    __syncthreads();

    if (tid < TILE_B) {
        float r = b2[0];
#pragma unroll
        for (int ww = 0; ww < 8; ++ww) r += s_part[tid][ww];
        out[p0 + tid] = r;
    }
}

// -------------------------------------------------------------------- launch
extern "C" void kernel_launch(void* const* d_in, const int* in_sizes, int n_in,
                              void* d_out, int out_size, void* d_ws, size_t ws_size,
                              hipStream_t stream) {
    const float* x   = (const float*)d_in[0];
    const int*   ei  = (const int*)d_in[1];
    const int*   tei = (const int*)d_in[2];
    const float* W1  = (const float*)d_in[3];
    const float* b1  = (const float*)d_in[4];
    const float* W2  = (const float*)d_in[5];
    const float* b2  = (const float*)d_in[6];
    float* out = (float*)d_out;

    unsigned char* ws = (unsigned char*)d_ws;
    const size_t adj_bytes = (size_t)N_NODES * WPR * sizeof(unsigned int);   // 12.8 MB
    unsigned int* adj = (unsigned int*)ws;
    short* W1B = (short*)(ws + adj_bytes);                                   // 128 KB bf16
    f32x4* K1  = (f32x4*)(ws + adj_bytes + 256 * 1024);                      // 8 MB

    zero_pack_kernel<<<ZERO_BLOCKS + PACK_BLOCKS, 256, 0, stream>>>((uint4*)adj, W1, W1B);
    mixed_kernel<<<XIJ_BLOCKS + BUILD_BLOCKS, 512, 0, stream>>>(x, tei, ei, adj, W1B, K1);
    fused2_kernel<<<XIJ_BLOCKS, 512, 0, stream>>>(x, tei, adj, W1B, K1, b1, W2, b2, out);
}

// Round 17
// 53.562 us; speedup vs baseline: 1.4742x; 1.0514x over previous
//
#include <hip/hip_runtime.h>

#define N_NODES 10000
#define N_EDGES 320000
#define N_PAIRS 8192
#define IN_CH   128
#define HIDDEN  256
#define K_DIM   256   // 2*IN_CH
#define WPR     320   // u32 words per adjacency bitset row (320*32 = 10240 >= 10000)
#define WPR4    (WPR / 4)
#define TILE_B  16    // pairs per block; grid 512, 512 threads/block
#define CN_CAP  128   // covers i==j pairs (cnt ~ Poisson(64)); overflow ~P<1e-15
#define ZERO_BLOCKS (N_NODES * WPR / 4 / 256)   // 3125 (uint4 units)
#define PACK_BLOCKS 32
#define ADJ_BLOCKS  (N_EDGES / 256)             // 1250

typedef __attribute__((ext_vector_type(8))) short  short8;   // 8 bf16 (4 VGPRs, 16 B)
typedef __attribute__((ext_vector_type(4))) short  short4v;  // 4 bf16 (8 B)
typedef __attribute__((ext_vector_type(4))) float  f32x4;    // MFMA accumulator

static __device__ inline short f2bf(float f) {
    union { float f; unsigned u; } c; c.f = f;
    unsigned r = (c.u + 0x7FFFu + ((c.u >> 16) & 1u)) >> 16;   // RNE
    return (short)r;
}

// ---------------------------------------------- zero adjacency + pack W1
// B-fragment for (k-step ks, n-tile t): lane l, elem e holds
//   W1[n = t*16 + (l&15)][k = ks*32 + (l>>4)*8 + e]   (bf16)
// at W1B[((ks*16 + t)*64 + l)*8 + e].
__global__ __launch_bounds__(256) void zero_pack_kernel(uint4* __restrict__ adj4,
                                                        const float* __restrict__ W1,
                                                        short* __restrict__ W1B) {
    int bid = blockIdx.x;
    int tid = threadIdx.x;
    if (bid < ZERO_BLOCKS) {
        adj4[(size_t)bid * 256 + tid] = make_uint4(0u, 0u, 0u, 0u);
    } else {
        int t2 = (bid - ZERO_BLOCKS) * 256 + tid;   // 0..8191
        int ks = t2 >> 10;                          // 0..7
        int t  = (t2 >> 6) & 15;                    // n-tile 0..15
        int l  = t2 & 63;                           // lane
        int n  = t * 16 + (l & 15);
        int kb = ks * 32 + ((l >> 4) << 3);
        const float* src = W1 + (size_t)n * K_DIM + kb;
        short* dst = W1B + ((size_t)(ks * 16 + t) * 64 + l) * 8;
#pragma unroll
        for (int e = 0; e < 8; ++e) dst[e] = f2bf(src[e]);
    }
}

// ---------------------------------------------------------------- adjacency
__global__ __launch_bounds__(256) void build_adj_kernel(const int* __restrict__ ei,
                                                        unsigned int* __restrict__ adj) {
    int e = blockIdx.x * blockDim.x + threadIdx.x;   // grid*block == N_EDGES exactly
    int u = ei[e];
    int v = ei[N_EDGES + e];
    atomicOr(&adj[(size_t)u * WPR + (v >> 5)], 1u << (v & 31));
    atomicOr(&adj[(size_t)v * WPR + (u >> 5)], 1u << (u & 31));
}

// ------------------------------------------------- fused pair-xs + MFMA MLP
// xs stored in LDS as bf16 A-fragment units (short8 = 8 channels = 16 B):
// units 0..15 = xij (k 0..127), units 16..31 = cn (k 128..255);
// unit u of pair-row r lives at s_xb[r*32 + (u ^ (r&7))]  (bank-balanced).
__global__ __launch_bounds__(512) void fused_kernel(const float* __restrict__ x,
                                                    const int* __restrict__ tei,
                                                    const unsigned int* __restrict__ adj,
                                                    const short* __restrict__ W1B,
                                                    const float* __restrict__ b1,
                                                    const float* __restrict__ W2,
                                                    const float* __restrict__ b2,
                                                    float* __restrict__ out) {
    __shared__ float4 s_cn[TILE_B * 32];      // fp32 CN slots (zero + overflow), 8 KB
    __shared__ short8 s_xb[TILE_B * 32];      // bf16 A-fragments, 8 KB
    __shared__ int    s_cnt[TILE_B];
    __shared__ int    s_cnl[TILE_B][CN_CAP];  // 8 KB
    __shared__ float  s_part[TILE_B][8];

    const int tid = threadIdx.x;
    const int p0 = blockIdx.x * TILE_B;

    if (tid < TILE_B) s_cnt[tid] = 0;
    s_cn[tid] = make_float4(0.f, 0.f, 0.f, 0.f);   // 512 threads = 16*32 slots
    __syncthreads();

    // ---- phase 1: intersection + xij (32 threads per pair; pair within one wave)
    const int b = tid >> 5;
    const int s = tid & 31;
    const int i = tei[p0 + b];             // 32-lane broadcast load
    const int j = tei[N_PAIRS + p0 + b];

    const float4* xi4 = (const float4*)(x + (size_t)i * IN_CH);
    const float4* xj4 = (const float4*)(x + (size_t)j * IN_CH);
    float4 va = xi4[s];                    // issue early
    float4 vb = xj4[s];

    const uint4* ri4 = (const uint4*)(adj + (size_t)i * WPR);
    const uint4* rj4 = (const uint4*)(adj + (size_t)j * WPR);
    for (int q = s; q < WPR4; q += 32) {   // 2-3 iterations
        uint4 a = ri4[q];
        uint4 c = rj4[q];
        unsigned int m[4] = { a.x & c.x, a.y & c.y, a.z & c.z, a.w & c.w };
#pragma unroll
        for (int ww = 0; ww < 4; ++ww) {
            unsigned int mm = m[ww];
            while (mm) {
                int bit = __builtin_ctz(mm);
                mm &= mm - 1;
                int n = q * 128 + ww * 32 + bit;
                int pos = atomicAdd(&s_cnt[b], 1);
                if (pos < CN_CAP) {
                    s_cnl[b][pos] = n;
                } else {
                    // overflow (deg>128 self-pair; ~never): fp32 LDS atomics
                    const float* xn = x + (size_t)n * IN_CH;
                    for (int d = 0; d < IN_CH; ++d)
                        atomicAdd(&((float*)&s_cn[b * 32 + (d >> 2)])[d & 3], xn[d]);
                }
            }
        }
    }

    // xij -> bf16 unit (s>>1), half (s&1)
    {
        short4v prod;
        prod[0] = f2bf(va.x * vb.x);
        prod[1] = f2bf(va.y * vb.y);
        prod[2] = f2bf(va.z * vb.z);
        prod[3] = f2bf(va.w * vb.w);
        ((short4v*)&s_xb[b * 32 + ((s >> 1) ^ (b & 7))])[s & 1] = prod;
    }

    // cn_emb: slot (zero + overflow) + list, 4 independent load chains; then bf16
    {
        int cnt = s_cnt[b];                // same-wave LDS ops: ordered
        if (cnt > CN_CAP) cnt = CN_CAP;
        float4 d0 = s_cn[b * 32 + s];
        float4 d1 = make_float4(0.f, 0.f, 0.f, 0.f);
        float4 d2 = make_float4(0.f, 0.f, 0.f, 0.f);
        float4 d3 = make_float4(0.f, 0.f, 0.f, 0.f);
        int c = 0;
        for (; c + 4 <= cnt; c += 4) {
            const float4* q0 = (const float4*)(x + (size_t)s_cnl[b][c]     * IN_CH);
            const float4* q1 = (const float4*)(x + (size_t)s_cnl[b][c + 1] * IN_CH);
            const float4* q2 = (const float4*)(x + (size_t)s_cnl[b][c + 2] * IN_CH);
            const float4* q3 = (const float4*)(x + (size_t)s_cnl[b][c + 3] * IN_CH);
            float4 v0 = q0[s], v1 = q1[s], v2 = q2[s], v3 = q3[s];
            d0 = make_float4(d0.x + v0.x, d0.y + v0.y, d0.z + v0.z, d0.w + v0.w);
            d1 = make_float4(d1.x + v1.x, d1.y + v1.y, d1.z + v1.z, d1.w + v1.w);
            d2 = make_float4(d2.x + v2.x, d2.y + v2.y, d2.z + v2.z, d2.w + v2.w);
            d3 = make_float4(d3.x + v3.x, d3.y + v3.y, d3.z + v3.z, d3.w + v3.w);
        }
        for (; c < cnt; ++c) {
            const float4* q0 = (const float4*)(x + (size_t)s_cnl[b][c] * IN_CH);
            float4 v0 = q0[s];
            d0 = make_float4(d0.x + v0.x, d0.y + v0.y, d0.z + v0.z, d0.w + v0.w);
        }
        d0 = make_float4(d0.x + d1.x + d2.x + d3.x,
                         d0.y + d1.y + d2.y + d3.y,
                         d0.z + d1.z + d2.z + d3.z,
                         d0.w + d1.w + d2.w + d3.w);
        short4v cv;
        cv[0] = f2bf(d0.x); cv[1] = f2bf(d0.y); cv[2] = f2bf(d0.z); cv[3] = f2bf(d0.w);
        ((short4v*)&s_xb[b * 32 + ((16 + (s >> 1)) ^ (b & 7))])[s & 1] = cv;
    }
    __syncthreads();

    // ---- phase 2: MFMA. wave w covers n-tiles {2w, 2w+1}, all 16 pairs.
    // A-frag = ONE ds_read_b128 per k-step (bf16 pre-converted in phase 1).
    const int w    = tid >> 6;       // wave 0..7
    const int lane = tid & 63;
    const int t0 = w * 2;
    const int mr = lane & 15;   // A row = pair
    const int kb = lane >> 4;   // k-block 0..3

    f32x4 acc0 = {0.f, 0.f, 0.f, 0.f};
    f32x4 acc1 = {0.f, 0.f, 0.f, 0.f};

    const short8* W1B8 = (const short8*)W1B;
#pragma unroll
    for (int ks = 0; ks < 8; ++ks) {
        short8 af = s_xb[mr * 32 + ((ks * 4 + kb) ^ (mr & 7))];
        int fb = (ks * 16 + t0) * 64 + lane;
        short8 bf0 = W1B8[fb];
        short8 bf1 = W1B8[fb + 64];
        acc0 = __builtin_amdgcn_mfma_f32_16x16x32_bf16(af, bf0, acc0, 0, 0, 0);
        acc1 = __builtin_amdgcn_mfma_f32_16x16x32_bf16(af, bf1, acc1, 0, 0, 0);
    }

    // ---- epilogue: relu + layer 2 (fp32), reduce over h
    // C layout: col = lane&15 (n within tile), row = (lane>>4)*4 + reg (pair)
    const int ncol = lane & 15;
    const float b10 = b1[t0 * 16 + ncol];
    const float b11 = b1[(t0 + 1) * 16 + ncol];
    const float w20 = W2[t0 * 16 + ncol];
    const float w21 = W2[(t0 + 1) * 16 + ncol];

    float sum[4];
#pragma unroll
    for (int r = 0; r < 4; ++r)
        sum[r] = w20 * fmaxf(acc0[r] + b10, 0.f) + w21 * fmaxf(acc1[r] + b11, 0.f);

#pragma unroll
    for (int r = 0; r < 4; ++r) {
        float v = sum[r];
        v += __shfl_xor(v, 1);
        v += __shfl_xor(v, 2);
        v += __shfl_xor(v, 4);
        v += __shfl_xor(v, 8);
        if ((lane & 15) == 0) s_part[kb * 4 + r][w] = v;
    }
    __syncthreads();

    if (tid < TILE_B) {
        float r = b2[0];
#pragma unroll
        for (int ww = 0; ww < 8; ++ww) r += s_part[tid][ww];
        out[p0 + tid] = r;
    }
}

// -------------------------------------------------------------------- launch
extern "C" void kernel_launch(void* const* d_in, const int* in_sizes, int n_in,
                              void* d_out, int out_size, void* d_ws, size_t ws_size,
                              hipStream_t stream) {
    const float* x   = (const float*)d_in[0];
    const int*   ei  = (const int*)d_in[1];
    const int*   tei = (const int*)d_in[2];
    const float* W1  = (const float*)d_in[3];
    const float* b1  = (const float*)d_in[4];
    const float* W2  = (const float*)d_in[5];
    const float* b2  = (const float*)d_in[6];
    float* out = (float*)d_out;

    unsigned char* ws = (unsigned char*)d_ws;
    const size_t adj_bytes = (size_t)N_NODES * WPR * sizeof(unsigned int);   // 12.8 MB
    unsigned int* adj = (unsigned int*)ws;
    short* W1B = (short*)(ws + adj_bytes);                                   // 128 KB bf16

    zero_pack_kernel<<<ZERO_BLOCKS + PACK_BLOCKS, 256, 0, stream>>>((uint4*)adj, W1, W1B);
    build_adj_kernel<<<ADJ_BLOCKS, 256, 0, stream>>>(ei, adj);
    fused_kernel<<<N_PAIRS / TILE_B, 512, 0, stream>>>(x, tei, adj, W1B, b1, W2, b2, out);
}